// Round 6
// baseline (741.373 us; speedup 1.0000x reference)
//
#include <hip/hip_runtime.h>
#include <hip/hip_bf16.h>

typedef float f32x4 __attribute__((ext_vector_type(4)));
typedef short bfx8 __attribute__((ext_vector_type(8)));   // 8 bf16 in 4 VGPRs

typedef const __attribute__((address_space(1))) void* gvp;
typedef __attribute__((address_space(3))) void* lvp;

static __device__ __forceinline__ unsigned short f2bf(float f) {
    return __builtin_bit_cast(unsigned short, __float2bfloat16(f));
}

static __device__ __forceinline__ ushort4 cvt4(f32x4 v) {
    return make_ushort4(f2bf(v[0]), f2bf(v[1]), f2bf(v[2]), f2bf(v[3]));
}

// ---------------------------------------------------------------------------
// Kernel 0: cast + transpose weights into WcatT[768][768] bf16.
// ---------------------------------------------------------------------------
__global__ void prep_w(const float* __restrict__ Wk, const float* __restrict__ Wq,
                       const float* __restrict__ Wv, unsigned short* __restrict__ WT) {
    const int n = blockIdx.x;       // 0..767
    const int e = threadIdx.x;      // 0..767
    const int which = n >> 8;
    const int h = n & 255;
    const float* W = (which == 0) ? Wq : (which == 1) ? Wk : Wv;
    WT[(size_t)n * 768 + e] = f2bf(W[(size_t)e * 256 + h]);
}

// ---------------------------------------------------------------------------
// Kernel 1: QKV = X @ [Wq|Wk|Wv].  256x256 tile, 8 waves (2M x 4N), BK=64,
// double-buffered 128KB LDS, 2-phase pipeline (stage kt+1 || compute kt,
// one barrier per kt).
//  - A (X rows, f32): reg-stage coalesced float4 -> cvt bf16 -> swizzled
//    ds_write. 256 m-rows span TWO batches (m0 = bm*256).
//  - B (WT rows): global_load_lds w16, linear dest, pre-swizzled source.
//  - bn 0/1/2 == Q/K/V exactly (tile n-width 256 = head dim).
//  - V (bn==2): operand-swapped MFMA -> D[n=h][m=t].
//  - Epilogue: fragments -> swizzled LDS (reusing the 128KB) -> fully
//    coalesced 16B/lane stores (kills the measured 2x write amplification).
// LDS byte map: Ab0 [0,32K) Ab1 [32K,64K) Bb0 [64K,96K) Bb1 [96K,128K);
// epilogue reuses all 128KB as C[256][512B].
// ---------------------------------------------------------------------------
__global__ __launch_bounds__(512, 2) void qkv_gemm(const float* __restrict__ X,
                                                   const unsigned short* __restrict__ WT,
                                                   unsigned short* __restrict__ QKV) {
    __shared__ __align__(16) char LDS[131072];

    const int tid = threadIdx.x;
    const int bid = blockIdx.x;                    // 0..767
    const int l   = (bid & 7) * 96 + (bid >> 3);   // bijective XCD remap (768%8==0)
    const int bn  = l % 3;                         // 0=Q 1=K 2=V
    const int bm  = l / 3;                         // 0..255
    const int m0 = bm * 256;
    const int n0 = bn * 256;
    const int w = tid >> 6, lane = tid & 63;
    const int wr = w >> 2, wc = w & 3;             // 2M x 4N wave grid
    const int lrow = lane & 15, lhi = lane >> 4;
    const bool vswap = (bn == 2);

    f32x4 acc[8][4];
    const f32x4 zero = {0.f, 0.f, 0.f, 0.f};
#pragma unroll
    for (int i = 0; i < 8; ++i)
#pragma unroll
        for (int j = 0; j < 4; ++j) acc[i][j] = zero;

    f32x4 areg[8];

    // ---- A: coalesced reg load (16 lanes x float4 = contiguous 256B/row-seg)
#define STAGE_A_LOAD(kt)                                                       \
    {                                                                          \
        const int k0s = (kt) * 64;                                             \
        _Pragma("unroll")                                                      \
        for (int i = 0; i < 8; ++i) {                                          \
            const int f = i * 512 + tid;                                       \
            const int row = f >> 4, col = (f & 15) * 4;                        \
            areg[i] = *(const f32x4*)(X + (size_t)(m0 + row) * 768 + k0s + col); \
        }                                                                      \
    }
    // ---- A: cvt + swizzled ds_write_b64 into Ab[bs] (rows 128B)
#define STAGE_A_WRITE(bs)                                                      \
    {                                                                          \
        _Pragma("unroll")                                                      \
        for (int i = 0; i < 8; ++i) {                                          \
            const int f = i * 512 + tid;                                       \
            const int row = f >> 4;                                            \
            const int cb  = (f & 15) * 8;                                      \
            const int cbs = cb ^ ((row & 7) << 4);                             \
            *(ushort4*)(LDS + (bs) * 32768 + row * 128 + cbs) = cvt4(areg[i]); \
        }                                                                      \
    }
    // ---- B: global_load_lds w16, linear dest, inverse-swizzled source
#define STAGE_B(kt, bs)                                                        \
    {                                                                          \
        const int k0s = (kt) * 64;                                             \
        _Pragma("unroll")                                                      \
        for (int i = 0; i < 4; ++i) {                                          \
            const int f = i * 512 + tid;                                       \
            const int row = f >> 3;                                            \
            const int cb  = (f & 7) * 16;                                      \
            const int cbs = cb ^ ((row & 7) << 4);                             \
            const unsigned short* g = WT + (size_t)(n0 + row) * 768 + k0s + (cbs >> 1); \
            char* lp = LDS + 65536 + (bs) * 32768 + i * 8192 + w * 1024;       \
            __builtin_amdgcn_global_load_lds((gvp)g, (lvp)lp, 16, 0, 0);       \
        }                                                                      \
    }

    // prologue
    STAGE_B(0, 0);
    STAGE_A_LOAD(0);
    STAGE_A_WRITE(0);
    __syncthreads();

    int cur = 0;
    for (int kt = 0; kt < 12; ++kt) {
        if (kt < 11) {
            STAGE_B(kt + 1, cur ^ 1);
            STAGE_A_LOAD(kt + 1);
        }
#pragma unroll
        for (int kk = 0; kk < 2; ++kk) {
            const int kb2 = (kk * 32 + lhi * 8) * 2;       // byte col in 128B row
            bfx8 a[8], bb4[4];
#pragma unroll
            for (int ni = 0; ni < 4; ++ni) {
                const int brow = wc * 64 + ni * 16 + lrow;
                bb4[ni] = *(const bfx8*)(LDS + 65536 + cur * 32768 + brow * 128 +
                                         (kb2 ^ ((brow & 7) << 4)));
            }
#pragma unroll
            for (int mi = 0; mi < 8; ++mi) {
                const int arow = wr * 128 + mi * 16 + lrow;
                a[mi] = *(const bfx8*)(LDS + cur * 32768 + arow * 128 +
                                       (kb2 ^ ((arow & 7) << 4)));
            }
            if (!vswap) {
#pragma unroll
                for (int mi = 0; mi < 8; ++mi)
#pragma unroll
                    for (int ni = 0; ni < 4; ++ni)
                        acc[mi][ni] = __builtin_amdgcn_mfma_f32_16x16x32_bf16(
                            a[mi], bb4[ni], acc[mi][ni], 0, 0, 0);
            } else {
#pragma unroll
                for (int mi = 0; mi < 8; ++mi)
#pragma unroll
                    for (int ni = 0; ni < 4; ++ni)
                        acc[mi][ni] = __builtin_amdgcn_mfma_f32_16x16x32_bf16(
                            bb4[ni], a[mi], acc[mi][ni], 0, 0, 0);   // D[n][m]
            }
        }
        if (kt < 11) STAGE_A_WRITE(cur ^ 1);
        __syncthreads();   // drains B DMA + A ds_writes; releases buffer cur
        cur ^= 1;
    }

    // ---- epilogue: fragments -> swizzled LDS C[256 rows][512B], then
    //      coalesced global stores. Row swizzle: byte ^= (row&7)<<4.
    if (!vswap) {
        // C row = trel (m), col = h*2 bytes
#pragma unroll
        for (int mi = 0; mi < 8; ++mi)
#pragma unroll
            for (int ni = 0; ni < 4; ++ni) {
                const int h2 = (wc * 64 + ni * 16 + lrow) * 2;
#pragma unroll
                for (int j = 0; j < 4; ++j) {
                    const int trel = wr * 128 + mi * 16 + lhi * 4 + j;
                    *(unsigned short*)(LDS + trel * 512 + (h2 ^ ((trel & 7) << 4))) =
                        f2bf(acc[mi][ni][j]);
                }
            }
    } else {
        // C row = h (n), col = trel*2 bytes  (V' = [h][t])
#pragma unroll
        for (int mi = 0; mi < 8; ++mi)
#pragma unroll
            for (int ni = 0; ni < 4; ++ni) {
                const int t2 = (wr * 128 + mi * 16 + lrow) * 2;
#pragma unroll
                for (int j = 0; j < 4; ++j) {
                    const int h = wc * 64 + ni * 16 + lhi * 4 + j;
                    *(unsigned short*)(LDS + h * 512 + (t2 ^ ((h & 7) << 4))) =
                        f2bf(acc[mi][ni][j]);
                }
            }
    }
    __syncthreads();

    // coalesced read-out: 16B/lane chunks, 128B per 16 consecutive lanes
#pragma unroll
    for (int i = 0; i < 16; ++i) {
        const int f = i * 512 + tid;
        const int r  = f >> 5;            // LDS row (trel for Q/K, h for V)
        const int c8 = (f & 31) * 8;      // element offset in row (0..248)
        const bfx8 v = *(const bfx8*)(LDS + r * 512 + ((c8 * 2) ^ ((r & 7) << 4)));
        if (bn < 2) {
            const int b = bm * 2 + (r >> 7);
            unsigned short* g = QKV + (((size_t)(b * 3 + bn)) << 15) +
                                (size_t)(r & 127) * 256 + c8;
            *(bfx8*)g = v;
        } else {
            const int b = bm * 2 + (c8 >> 7);
            unsigned short* g = QKV + (((size_t)(b * 3 + 2)) << 15) +
                                (size_t)r * 128 + (c8 & 127);
            *(bfx8*)g = v;
        }
    }
}

// ---------------------------------------------------------------------------
// Kernel 2: per-batch causal attention (unchanged — passing, ~10µs).
// ---------------------------------------------------------------------------
__global__ __launch_bounds__(512) void attn(const unsigned short* __restrict__ QKV,
                                            float* __restrict__ Out) {
    __shared__ unsigned short Kl[128][264];
    __shared__ unsigned short Vt[256][136];

    const int b = blockIdx.x;
    const int tid = threadIdx.x;
    const int w = tid >> 6, lane = tid & 63;
    const int lrow = lane & 15, lhi = lane >> 4;

    const unsigned short* Qb = QKV + ((size_t)(b * 3 + 0) << 15);
    const unsigned short* Kb = QKV + ((size_t)(b * 3 + 1) << 15);
    const unsigned short* Vb = QKV + ((size_t)(b * 3 + 2) << 15);

    const int t0 = w * 16;
    bfx8 aq[8];
#pragma unroll
    for (int kk = 0; kk < 8; ++kk)
        aq[kk] = *(const bfx8*)(Qb + (size_t)(t0 + lrow) * 256 + kk * 32 + lhi * 8);

#pragma unroll
    for (int i = 0; i < 8; ++i) {
        int f = i * 512 + tid;
        {
            int row = f >> 5, c = (f & 31) * 8;
            *(bfx8*)&Kl[row][c] = *(const bfx8*)(Kb + (size_t)row * 256 + c);
        }
        {
            int row = f >> 4, c = (f & 15) * 8;
            *(bfx8*)&Vt[row][c] = *(const bfx8*)(Vb + (size_t)row * 128 + c);
        }
    }
    __syncthreads();

    f32x4 sacc[8];
    const f32x4 zero = {0.f, 0.f, 0.f, 0.f};
#pragma unroll
    for (int sj = 0; sj < 8; ++sj) sacc[sj] = zero;
#pragma unroll
    for (int kk = 0; kk < 8; ++kk) {
        const int kb = kk * 32 + lhi * 8;
#pragma unroll
        for (int sj = 0; sj < 8; ++sj) {
            bfx8 bk = *(const bfx8*)&Kl[sj * 16 + lrow][kb];
            sacc[sj] = __builtin_amdgcn_mfma_f32_16x16x32_bf16(aq[kk], bk, sacc[sj], 0, 0, 0);
        }
    }

    const float scale = 0.03608439182435161f;   // 1/sqrt(768)
    float inv[4];
#pragma unroll
    for (int j = 0; j < 4; ++j) {
        const int t = t0 + lhi * 4 + j;
        float m = -1e30f;
#pragma unroll
        for (int sj = 0; sj < 8; ++sj) {
            int s = sj * 16 + lrow;
            float vv = sacc[sj][j] * scale;
            vv = (s <= t) ? vv : -1e30f;
            sacc[sj][j] = vv;
            m = fmaxf(m, vv);
        }
#pragma unroll
        for (int d = 1; d < 16; d <<= 1) m = fmaxf(m, __shfl_xor(m, d));
        float sum = 0.f;
#pragma unroll
        for (int sj = 0; sj < 8; ++sj) {
            float e = __expf(sacc[sj][j] - m);
            sacc[sj][j] = e;
            sum += e;
        }
#pragma unroll
        for (int d = 1; d < 16; d <<= 1) sum += __shfl_xor(sum, d);
        inv[j] = 1.0f / sum;
    }

    __syncthreads();

    unsigned short* Pl = &Kl[0][0] + (size_t)w * (16 * 136);
#pragma unroll
    for (int sj = 0; sj < 8; ++sj)
#pragma unroll
        for (int j = 0; j < 4; ++j)
            Pl[(lhi * 4 + j) * 136 + sj * 16 + lrow] = f2bf(sacc[sj][j] * inv[j]);

    bfx8 pa[4];
#pragma unroll
    for (int kk = 0; kk < 4; ++kk)
        pa[kk] = *(const bfx8*)(Pl + lrow * 136 + kk * 32 + lhi * 8);

    f32x4 oacc[16];
#pragma unroll
    for (int ni = 0; ni < 16; ++ni) oacc[ni] = zero;
#pragma unroll
    for (int ni = 0; ni < 16; ++ni) {
#pragma unroll
        for (int kk = 0; kk < 4; ++kk) {
            bfx8 bv = *(const bfx8*)&Vt[ni * 16 + lrow][kk * 32 + lhi * 8];
            oacc[ni] = __builtin_amdgcn_mfma_f32_16x16x32_bf16(pa[kk], bv, oacc[ni], 0, 0, 0);
        }
    }

    float* Ob = Out + (size_t)b * 128 * 256;
#pragma unroll
    for (int ni = 0; ni < 16; ++ni) {
#pragma unroll
        for (int j = 0; j < 4; ++j) {
            const int t = t0 + lhi * 4 + j;
            const int h = ni * 16 + lrow;
            Ob[(size_t)t * 256 + h] = oacc[ni][j];
        }
    }
}

// ---------------------------------------------------------------------------
extern "C" void kernel_launch(void* const* d_in, const int* in_sizes, int n_in,
                              void* d_out, int out_size, void* d_ws, size_t ws_size,
                              hipStream_t stream) {
    (void)in_sizes; (void)n_in; (void)out_size; (void)ws_size;
    const float* X  = (const float*)d_in[0];   // res_stream [512,128,768]
    const float* Wk = (const float*)d_in[1];   // [768,256]
    const float* Wq = (const float*)d_in[2];
    const float* Wv = (const float*)d_in[3];

    unsigned short* WT  = (unsigned short*)d_ws;          // 768*768 bf16
    unsigned short* QKV = WT + (size_t)768 * 768;         // 512*3*32768 bf16
    float* Out = (float*)d_out;

    prep_w<<<768, 768, 0, stream>>>(Wk, Wq, Wv, WT);
    qkv_gemm<<<768, 512, 0, stream>>>(X, WT, QKV);
    attn<<<512, 512, 0, stream>>>(QKV, Out);
}